// Round 3
// baseline (3715.200 us; speedup 1.0000x reference)
//
#include <hip/hip_runtime.h>
#include <stdint.h>

#define NB 2048
#define NW 6
#define ND 1024
#define NH 8
#define NDH 128
#define NTOT 12582912u
#define BT 128            // threads per step-kernel block (2 waves)
#define C_DT 0.09f
#define C_COUP 0.01f
#define C_TOL 0.05f
#define C_THIGH 0.22f
#define NSTEPS 16

struct Flags {
  int done; int apply_noise; int cnt_low; int cnt_high; int arrived;
  float sum_T;
};

__host__ __device__ __forceinline__ uint32_t rotl32(uint32_t x, uint32_t d) {
  return (x << d) | (x >> (32u - d));
}

// JAX threefry2x32 (20 rounds), matches jax/_src/prng.py
__host__ __device__ __forceinline__ void tf2x32(uint32_t k0, uint32_t k1,
                                                uint32_t x0, uint32_t x1,
                                                uint32_t& o0, uint32_t& o1) {
  const uint32_t k2 = k0 ^ k1 ^ 0x1BD11BDAu;
#define TF_R4(a,b,c,d) \
  x0 += x1; x1 = rotl32(x1,a); x1 ^= x0; \
  x0 += x1; x1 = rotl32(x1,b); x1 ^= x0; \
  x0 += x1; x1 = rotl32(x1,c); x1 ^= x0; \
  x0 += x1; x1 = rotl32(x1,d); x1 ^= x0;
  x0 += k0; x1 += k1;
  TF_R4(13u,15u,26u,6u)  x0 += k1; x1 += k2 + 1u;
  TF_R4(17u,29u,16u,24u) x0 += k2; x1 += k0 + 2u;
  TF_R4(13u,15u,26u,6u)  x0 += k0; x1 += k1 + 3u;
  TF_R4(17u,29u,16u,24u) x0 += k1; x1 += k2 + 4u;
  TF_R4(13u,15u,26u,6u)  x0 += k2; x1 += k0 + 5u;
#undef TF_R4
  o0 = x0; o1 = x1;
}

// XLA ErfInv32 (Giles) polynomial — matches xla/client/lib/math.cc
__device__ __forceinline__ float erfinv_xla(float x) {
  const float w = -log1pf(-x * x);
  float ps, pb;
  const float ws = w - 2.5f;
  ps = 2.81022636e-08f;
  ps = fmaf(ps, ws, 3.43273939e-07f);
  ps = fmaf(ps, ws, -3.5233877e-06f);
  ps = fmaf(ps, ws, -4.39150654e-06f);
  ps = fmaf(ps, ws, 0.00021858087f);
  ps = fmaf(ps, ws, -0.00125372503f);
  ps = fmaf(ps, ws, -0.00417768164f);
  ps = fmaf(ps, ws, 0.246640727f);
  ps = fmaf(ps, ws, 1.50140941f);
  const float wb = sqrtf(w) - 3.0f;
  pb = -0.000200214257f;
  pb = fmaf(pb, wb, 0.000100950558f);
  pb = fmaf(pb, wb, 0.00134934322f);
  pb = fmaf(pb, wb, -0.00367342844f);
  pb = fmaf(pb, wb, 0.00573950773f);
  pb = fmaf(pb, wb, -0.0076224613f);
  pb = fmaf(pb, wb, 0.00943887047f);
  pb = fmaf(pb, wb, 1.00167406f);
  pb = fmaf(pb, wb, 2.83297682f);
  const float p = (w < 5.0f) ? ps : pb;
  return p * x;
}

__device__ __forceinline__ float noise_z(uint32_t k0, uint32_t k1, uint32_t p) {
  // JAX threefry_partitionable: counter (hi=0, lo=p), bits = o0 ^ o1
  uint32_t o0, o1;
  tf2x32(k0, k1, 0u, p, o0, o1);
  const uint32_t bits = o0 ^ o1;
  const float f = __uint_as_float((bits >> 9) | 0x3F800000u) - 1.0f;
  const float lo = -0.99999994f;                 // nextafter(-1,0) in f32
  const float u = fmaxf(lo, fmaf(f, 2.0f, lo));
  return 1.41421356237f * erfinv_xla(u);
}

// block reduce for BT=128 (2 waves)
__device__ __forceinline__ float block_sum2(float v, float* red) {
  #pragma unroll
  for (int off = 32; off > 0; off >>= 1) v += __shfl_down(v, off, 64);
  const int t = threadIdx.x;
  __syncthreads();
  if ((t & 63) == 0) red[t >> 6] = v;
  __syncthreads();
  return red[0] + red[1];
}

// block reduce for 256-thread blocks (trailing noise kernel)
__device__ __forceinline__ float block_sum4(float v, float* red) {
  #pragma unroll
  for (int off = 32; off > 0; off >>= 1) v += __shfl_down(v, off, 64);
  const int t = threadIdx.x;
  __syncthreads();
  if ((t & 63) == 0) red[t >> 6] = v;
  __syncthreads();
  return red[0] + red[1] + red[2] + red[3];
}

__global__ void init_kernel(Flags* f, float* curve) {
  const int t = threadIdx.x;
  if (t == 0) {
    f->done = 0; f->apply_noise = 0;
    f->cnt_low = 0; f->cnt_high = 0; f->arrived = 0; f->sum_T = 0.0f;
  }
  if (t < NSTEPS) curve[t] = __int_as_float(0x7FC00000);   // NaN
}

// M[h][d][e] = sum_r U[h][d][r] * V[h][r][e]
__global__ __launch_bounds__(128) void precompute_M(const float* __restrict__ U,
                                                    const float* __restrict__ V,
                                                    float* __restrict__ M) {
  const int hd = blockIdx.x;          // h*128 + d
  const int h = hd >> 7;
  const int e = threadIdx.x;
  __shared__ float u[64];
  if (e < 64) u[e] = U[hd * 64 + e];
  __syncthreads();
  float acc = 0.0f;
  #pragma unroll
  for (int r = 0; r < 64; ++r)
    acc = fmaf(u[r], V[(h * 64 + r) * 128 + e], acc);
  M[hd * 128 + e] = acc;
}

// Fused per-step kernel: (pending noise from previous step) + Euler drift +
// clamp_norm + tension stats; last-block computes the global flags update.
__global__ __launch_bounds__(BT) void step_kernel(
    const float* __restrict__ Sin, float* __restrict__ Sout,
    const float* __restrict__ signal, const float* __restrict__ M,
    Flags* __restrict__ flags, float* __restrict__ curve,
    const int step_k, const uint32_t nk0, const uint32_t nk1,
    const int has_noise) {
  if (flags->done) return;
  __shared__ __align__(16) float xs[NW][ND];     // 24 KB
  __shared__ __align__(16) float mh[NW][NDH];    // 3 KB
  __shared__ float red[2];
  const int t = threadIdx.x;
  const int b = blockIdx.x;

  // ---- phase 1: load rows (8 cols/thread), apply pending noise ----
  const int le0 = t << 3;
  float v[NW][8];
  #pragma unroll
  for (int w = 0; w < NW; ++w) {
    const float* src = Sin + (size_t)(b * NW + w) * ND + le0;
    const float4 a = *reinterpret_cast<const float4*>(src);
    const float4 c = *reinterpret_cast<const float4*>(src + 4);
    v[w][0]=a.x; v[w][1]=a.y; v[w][2]=a.z; v[w][3]=a.w;
    v[w][4]=c.x; v[w][5]=c.y; v[w][6]=c.z; v[w][7]=c.w;
  }
  if (has_noise && flags->apply_noise) {
    #pragma unroll
    for (int w = 0; w < NW; ++w) {
      const uint32_t rowbase = (uint32_t)(b * NW + w) * ND + (uint32_t)le0;
      #pragma unroll
      for (int j = 0; j < 8; ++j)
        v[w][j] = fmaf(0.01f, noise_z(nk0, nk1, rowbase + (uint32_t)j), v[w][j]);
    }
    #pragma unroll 1
    for (int w = 0; w < NW; ++w) {
      float p2 = 0.0f;
      #pragma unroll
      for (int j = 0; j < 8; ++j) p2 = fmaf(v[w][j], v[w][j], p2);
      const float n2 = block_sum2(p2, red);
      const float inv = 1.0f / (sqrtf(n2) + 1e-8f);
      #pragma unroll
      for (int j = 0; j < 8; ++j) v[w][j] *= inv;
    }
  }
  #pragma unroll
  for (int w = 0; w < NW; ++w) {
    float4 a, c;
    a.x=v[w][0]; a.y=v[w][1]; a.z=v[w][2]; a.w=v[w][3];
    c.x=v[w][4]; c.y=v[w][5]; c.z=v[w][6]; c.w=v[w][7];
    *reinterpret_cast<float4*>(&xs[w][le0])     = a;
    *reinterpret_cast<float4*>(&xs[w][le0 + 4]) = c;
  }
  __syncthreads();

  // ---- phase 2: cross-head mean (coupling) ----
  for (int idx = t; idx < NW * NDH; idx += BT) {     // 6 iters
    const int w = idx >> 7, el = idx & 127;
    float s = 0.0f;
    #pragma unroll
    for (int hh = 0; hh < NH; ++hh) s += xs[w][hh * NDH + el];
    mh[w][el] = s * 0.125f;
  }
  __syncthreads();

  // ---- phase 3: drift matmul  acc[w][j] = sum_d x[w][h*128+d] * M[h][d][el0+j]
  const int h   = t >> 4;             // head (0..7)
  const int el0 = (t & 15) << 3;      // 8 cols within head
  float acc[NW][8];
  #pragma unroll
  for (int w = 0; w < NW; ++w)
    #pragma unroll
    for (int j = 0; j < 8; ++j) acc[w][j] = 0.0f;

  const float* Mrow = M + ((size_t)h * NDH) * NDH + el0;   // advance by NDH per d
  #pragma unroll 2
  for (int d4 = 0; d4 < NDH / 4; ++d4) {
    float xv[NW][4];
    #pragma unroll
    for (int w = 0; w < NW; ++w) {
      const float4 q = *reinterpret_cast<const float4*>(&xs[w][h * NDH + (d4 << 2)]);
      xv[w][0]=q.x; xv[w][1]=q.y; xv[w][2]=q.z; xv[w][3]=q.w;
    }
    #pragma unroll
    for (int jj = 0; jj < 4; ++jj) {
      const float4 m0 = *reinterpret_cast<const float4*>(Mrow);
      const float4 m1 = *reinterpret_cast<const float4*>(Mrow + 4);
      Mrow += NDH;
      #pragma unroll
      for (int w = 0; w < NW; ++w) {
        const float xd = xv[w][jj];
        acc[w][0] = fmaf(xd, m0.x, acc[w][0]);
        acc[w][1] = fmaf(xd, m0.y, acc[w][1]);
        acc[w][2] = fmaf(xd, m0.z, acc[w][2]);
        acc[w][3] = fmaf(xd, m0.w, acc[w][3]);
        acc[w][4] = fmaf(xd, m1.x, acc[w][4]);
        acc[w][5] = fmaf(xd, m1.y, acc[w][5]);
        acc[w][6] = fmaf(xd, m1.z, acc[w][6]);
        acc[w][7] = fmaf(xd, m1.w, acc[w][7]);
      }
    }
  }

  // ---- phase 4: Euler step on this thread's 8 cols ----
  const int ge0 = h * NDH + el0;      // global col base for compute phase
  #pragma unroll
  for (int w = 0; w < NW; ++w) {
    const float* sg = signal + (size_t)(b * NW + w) * ND + ge0;
    const float4 s0 = *reinterpret_cast<const float4*>(sg);
    const float4 s1 = *reinterpret_cast<const float4*>(sg + 4);
    const float4 x0 = *reinterpret_cast<const float4*>(&xs[w][ge0]);
    const float4 x1 = *reinterpret_cast<const float4*>(&xs[w][ge0 + 4]);
    const float4 h0 = *reinterpret_cast<const float4*>(&mh[w][el0]);
    const float4 h1 = *reinterpret_cast<const float4*>(&mh[w][el0 + 4]);
    const float sgf[8] = {s0.x,s0.y,s0.z,s0.w,s1.x,s1.y,s1.z,s1.w};
    const float xxf[8] = {x0.x,x0.y,x0.z,x0.w,x1.x,x1.y,x1.z,x1.w};
    const float mhf[8] = {h0.x,h0.y,h0.z,h0.w,h1.x,h1.y,h1.z,h1.w};
    #pragma unroll
    for (int j = 0; j < 8; ++j) {
      const float out = -acc[w][j] + C_COUP * (mhf[j] - xxf[j]) + sgf[j];
      acc[w][j] = fmaf(C_DT, out, xxf[j]);
    }
  }

  // ---- phase 5: clamp_norm, write Sn, stash normed rows in xs ----
  #pragma unroll 1
  for (int w = 0; w < NW; ++w) {
    float p = 0.0f;
    #pragma unroll
    for (int j = 0; j < 8; ++j) p = fmaf(acc[w][j], acc[w][j], p);
    const float n2 = block_sum2(p, red);
    const float n = sqrtf(n2);
    const float scale = fminf(fmaxf(n, 1e-3f), 12.0f) / fmaxf(n, 1e-8f);
    const float inv_norm = 1.0f / (n * scale + 1e-12f);
    float4 o0, o1, q0, q1;
    o0.x=acc[w][0]*scale; o0.y=acc[w][1]*scale; o0.z=acc[w][2]*scale; o0.w=acc[w][3]*scale;
    o1.x=acc[w][4]*scale; o1.y=acc[w][5]*scale; o1.z=acc[w][6]*scale; o1.w=acc[w][7]*scale;
    float* dst = Sout + (size_t)(b * NW + w) * ND + ge0;
    *reinterpret_cast<float4*>(dst)     = o0;
    *reinterpret_cast<float4*>(dst + 4) = o1;
    q0.x=o0.x*inv_norm; q0.y=o0.y*inv_norm; q0.z=o0.z*inv_norm; q0.w=o0.w*inv_norm;
    q1.x=o1.x*inv_norm; q1.y=o1.y*inv_norm; q1.z=o1.z*inv_norm; q1.w=o1.w*inv_norm;
    *reinterpret_cast<float4*>(&xs[w][ge0])     = q0;
    *reinterpret_cast<float4*>(&xs[w][ge0 + 4]) = q1;
  }
  __syncthreads();

  // ---- phase 6: tension T(b) = 1 - mean_w <normed_w, mean_dir> ----
  float vals[NW][8];
  #pragma unroll
  for (int w = 0; w < NW; ++w) {
    const float4 a0 = *reinterpret_cast<const float4*>(&xs[w][ge0]);
    const float4 a1 = *reinterpret_cast<const float4*>(&xs[w][ge0 + 4]);
    vals[w][0]=a0.x; vals[w][1]=a0.y; vals[w][2]=a0.z; vals[w][3]=a0.w;
    vals[w][4]=a1.x; vals[w][5]=a1.y; vals[w][6]=a1.z; vals[w][7]=a1.w;
  }
  float pc[NW];
  #pragma unroll
  for (int w = 0; w < NW; ++w) pc[w] = 0.0f;
  #pragma unroll
  for (int j = 0; j < 8; ++j) {
    float md = 0.0f;
    #pragma unroll
    for (int w = 0; w < NW; ++w) md += vals[w][j];
    md *= (1.0f / 6.0f);
    #pragma unroll
    for (int w = 0; w < NW; ++w) pc[w] = fmaf(vals[w][j], md, pc[w]);
  }
  float cos_sum = 0.0f;
  #pragma unroll 1
  for (int w = 0; w < NW; ++w) cos_sum += block_sum2(pc[w], red);

  if (t == 0) {
    const float T = 1.0f - cos_sum * (1.0f / 6.0f);
    atomicAdd(&flags->sum_T, T);
    if (T < C_TOL)   atomicAdd(&flags->cnt_low, 1);
    if (T > C_THIGH) atomicAdd(&flags->cnt_high, 1);
    __threadfence();
    const int ticket = atomicAdd(&flags->arrived, 1);
    if (ticket == NB - 1) {
      // last block: read totals (atomic RMW for cross-XCD coherence)
      const float sT = atomicAdd(&flags->sum_T, 0.0f);
      const int cl = atomicAdd(&flags->cnt_low, 0);
      const int ch = atomicAdd(&flags->cnt_high, 0);
      curve[step_k] = sT * (1.0f / 2048.0f);
      const int nd = (cl == NB) ? 1 : 0;
      flags->apply_noise = (!nd && ch > 0) ? 1 : 0;
      flags->done = nd;
      flags->sum_T = 0.0f; flags->cnt_low = 0; flags->cnt_high = 0;
      flags->arrived = 0;
      __threadfence();
    }
  }
}

// trailing noise for the final step (pending noise not consumed by a next step)
__global__ __launch_bounds__(256) void noise_kernel(float* __restrict__ S,
                                                    const Flags* __restrict__ flags,
                                                    const uint32_t k0, const uint32_t k1) {
  if (!flags->apply_noise) return;
  __shared__ float red[4];
  const int t = threadIdx.x;
  const uint32_t base = (uint32_t)blockIdx.x * ND + (t << 2);
  const float4 s = *reinterpret_cast<const float4*>(S + base);
  float v[4] = {s.x, s.y, s.z, s.w};
  #pragma unroll
  for (int j = 0; j < 4; ++j)
    v[j] = fmaf(0.01f, noise_z(k0, k1, base + (uint32_t)j), v[j]);
  const float p2 = v[0]*v[0] + v[1]*v[1] + v[2]*v[2] + v[3]*v[3];
  const float n2 = block_sum4(p2, red);
  const float inv = 1.0f / (sqrtf(n2) + 1e-8f);
  float4 o;
  o.x = v[0]*inv; o.y = v[1]*inv; o.z = v[2]*inv; o.w = v[3]*inv;
  *reinterpret_cast<float4*>(S + base) = o;
}

extern "C" void kernel_launch(void* const* d_in, const int* in_sizes, int n_in,
                              void* d_out, int out_size, void* d_ws, size_t ws_size,
                              hipStream_t stream) {
  const float* S0     = (const float*)d_in[0];
  const float* signal = (const float*)d_in[1];
  const float* U      = (const float*)d_in[2];
  const float* V      = (const float*)d_in[3];
  float* out   = (float*)d_out;
  float* curve = out + NTOT;
  Flags* flags = (Flags*)d_ws;
  float* M = (float*)((char*)d_ws + 512);   // 512 KB for M, after flags

  init_kernel<<<1, 32, 0, stream>>>(flags, curve);
  precompute_M<<<NH * NDH, 128, 0, stream>>>(U, V, M);

  // fold_in(key(1), k) for k=0..15 on host: threefry((0,1), (0,k))
  uint32_t K0[NSTEPS], K1[NSTEPS];
  for (uint32_t k = 0; k < NSTEPS; ++k) tf2x32(0u, 1u, 0u, k, K0[k], K1[k]);

  for (int k = 0; k < NSTEPS; ++k) {
    // step k consumes the pending noise of step k-1 (key K[k-1])
    step_kernel<<<NB, BT, 0, stream>>>(
        k == 0 ? S0 : out, out, signal, M, flags, curve, k,
        k > 0 ? K0[k - 1] : 0u, k > 0 ? K1[k - 1] : 0u, k > 0 ? 1 : 0);
  }
  noise_kernel<<<NB * NW, 256, 0, stream>>>(out, flags, K0[NSTEPS - 1], K1[NSTEPS - 1]);
}

// Round 4
// 2370.316 us; speedup vs baseline: 1.5674x; 1.5674x over previous
//
#include <hip/hip_runtime.h>
#include <stdint.h>

#define NB 2048
#define NW 6
#define ND 1024
#define NH 8
#define NDH 128
#define NTOT 12582912u
#define BT 256            // threads per step-kernel block (4 waves)
#define C_DT 0.09f
#define C_COUP 0.01f
#define C_TOL 0.05f
#define C_THIGH 0.22f
#define NSTEPS 16

struct Flags {
  int done; int apply_noise; int cnt_low; int cnt_high; int arrived;
  float sum_T;
};

__host__ __device__ __forceinline__ uint32_t rotl32(uint32_t x, uint32_t d) {
  return (x << d) | (x >> (32u - d));
}

// JAX threefry2x32 (20 rounds), matches jax/_src/prng.py
__host__ __device__ __forceinline__ void tf2x32(uint32_t k0, uint32_t k1,
                                                uint32_t x0, uint32_t x1,
                                                uint32_t& o0, uint32_t& o1) {
  const uint32_t k2 = k0 ^ k1 ^ 0x1BD11BDAu;
#define TF_R4(a,b,c,d) \
  x0 += x1; x1 = rotl32(x1,a); x1 ^= x0; \
  x0 += x1; x1 = rotl32(x1,b); x1 ^= x0; \
  x0 += x1; x1 = rotl32(x1,c); x1 ^= x0; \
  x0 += x1; x1 = rotl32(x1,d); x1 ^= x0;
  x0 += k0; x1 += k1;
  TF_R4(13u,15u,26u,6u)  x0 += k1; x1 += k2 + 1u;
  TF_R4(17u,29u,16u,24u) x0 += k2; x1 += k0 + 2u;
  TF_R4(13u,15u,26u,6u)  x0 += k0; x1 += k1 + 3u;
  TF_R4(17u,29u,16u,24u) x0 += k1; x1 += k2 + 4u;
  TF_R4(13u,15u,26u,6u)  x0 += k2; x1 += k0 + 5u;
#undef TF_R4
  o0 = x0; o1 = x1;
}

// XLA ErfInv32 (Giles) polynomial — matches xla/client/lib/math.cc
__device__ __forceinline__ float erfinv_xla(float x) {
  const float w = -log1pf(-x * x);
  float ps, pb;
  const float ws = w - 2.5f;
  ps = 2.81022636e-08f;
  ps = fmaf(ps, ws, 3.43273939e-07f);
  ps = fmaf(ps, ws, -3.5233877e-06f);
  ps = fmaf(ps, ws, -4.39150654e-06f);
  ps = fmaf(ps, ws, 0.00021858087f);
  ps = fmaf(ps, ws, -0.00125372503f);
  ps = fmaf(ps, ws, -0.00417768164f);
  ps = fmaf(ps, ws, 0.246640727f);
  ps = fmaf(ps, ws, 1.50140941f);
  const float wb = sqrtf(w) - 3.0f;
  pb = -0.000200214257f;
  pb = fmaf(pb, wb, 0.000100950558f);
  pb = fmaf(pb, wb, 0.00134934322f);
  pb = fmaf(pb, wb, -0.00367342844f);
  pb = fmaf(pb, wb, 0.00573950773f);
  pb = fmaf(pb, wb, -0.0076224613f);
  pb = fmaf(pb, wb, 0.00943887047f);
  pb = fmaf(pb, wb, 1.00167406f);
  pb = fmaf(pb, wb, 2.83297682f);
  const float p = (w < 5.0f) ? ps : pb;
  return p * x;
}

__device__ __forceinline__ float noise_z(uint32_t k0, uint32_t k1, uint32_t p) {
  // JAX threefry_partitionable: counter (hi=0, lo=p), bits = o0 ^ o1
  uint32_t o0, o1;
  tf2x32(k0, k1, 0u, p, o0, o1);
  const uint32_t bits = o0 ^ o1;
  const float f = __uint_as_float((bits >> 9) | 0x3F800000u) - 1.0f;
  const float lo = -0.99999994f;                 // nextafter(-1,0) in f32
  const float u = fmaxf(lo, fmaf(f, 2.0f, lo));
  return 1.41421356237f * erfinv_xla(u);
}

// Batched 6-value block reduction for BT=256 (4 waves): 36 shuffles, 2 syncs.
__device__ __forceinline__ void block_sum6(float p[NW], float* red /*[4*NW]*/) {
  #pragma unroll
  for (int w = 0; w < NW; ++w)
    #pragma unroll
    for (int off = 32; off > 0; off >>= 1) p[w] += __shfl_down(p[w], off, 64);
  const int t = threadIdx.x;
  __syncthreads();                       // protect red from previous use
  if ((t & 63) == 0) {
    #pragma unroll
    for (int w = 0; w < NW; ++w) red[(t >> 6) * NW + w] = p[w];
  }
  __syncthreads();
  #pragma unroll
  for (int w = 0; w < NW; ++w)
    p[w] = red[w] + red[NW + w] + red[2 * NW + w] + red[3 * NW + w];
}

// single-value block reduce for 256-thread trailing noise kernel
__device__ __forceinline__ float block_sum4(float v, float* red) {
  #pragma unroll
  for (int off = 32; off > 0; off >>= 1) v += __shfl_down(v, off, 64);
  const int t = threadIdx.x;
  __syncthreads();
  if ((t & 63) == 0) red[t >> 6] = v;
  __syncthreads();
  return red[0] + red[1] + red[2] + red[3];
}

__global__ void init_kernel(Flags* f, float* curve) {
  const int t = threadIdx.x;
  if (t == 0) {
    f->done = 0; f->apply_noise = 0;
    f->cnt_low = 0; f->cnt_high = 0; f->arrived = 0; f->sum_T = 0.0f;
  }
  if (t < NSTEPS) curve[t] = __int_as_float(0x7FC00000);   // NaN
}

// M[h][d][e] = sum_r U[h][d][r] * V[h][r][e]
__global__ __launch_bounds__(128) void precompute_M(const float* __restrict__ U,
                                                    const float* __restrict__ V,
                                                    float* __restrict__ M) {
  const int hd = blockIdx.x;          // h*128 + d
  const int h = hd >> 7;
  const int e = threadIdx.x;
  __shared__ float u[64];
  if (e < 64) u[e] = U[hd * 64 + e];
  __syncthreads();
  float acc = 0.0f;
  #pragma unroll
  for (int r = 0; r < 64; ++r)
    acc = fmaf(u[r], V[(h * 64 + r) * 128 + e], acc);
  M[hd * 128 + e] = acc;
}

// Fused per-step kernel: (pending noise of previous step) + Euler drift +
// clamp_norm + tension; last-block ticket updates the global flags.
// Geometry: BT=256, 4 cols/thread; e0 = t*4 == (t>>5)*128 + (t&31)*4, so the
// load-phase and matmul-phase column ownership coincide.
__global__ __launch_bounds__(BT, 4) void step_kernel(
    const float* __restrict__ Sin, float* __restrict__ Sout,
    const float* __restrict__ signal, const float* __restrict__ M,
    Flags* __restrict__ flags, float* __restrict__ curve,
    const int step_k, const uint32_t nk0, const uint32_t nk1,
    const int has_noise) {
  if (flags->done) return;
  __shared__ __align__(16) float xs[NW][ND];     // 24 KB
  __shared__ __align__(16) float mh[NW][NDH];    // 3 KB
  __shared__ float red[4 * NW];
  const int t = threadIdx.x;
  const int b = blockIdx.x;
  const int e0 = t << 2;              // 4 cols per thread
  const int h  = t >> 5;              // head (32 threads/head)
  const int lc = t & 31;              // float4-column within head

  // ---- phase 1: load rows, apply pending noise, stage to LDS ----
  float v[NW][4];
  #pragma unroll
  for (int w = 0; w < NW; ++w) {
    const float4 a = *reinterpret_cast<const float4*>(
        Sin + (size_t)(b * NW + w) * ND + e0);
    v[w][0]=a.x; v[w][1]=a.y; v[w][2]=a.z; v[w][3]=a.w;
  }
  if (has_noise && flags->apply_noise) {
    float p[NW];
    #pragma unroll
    for (int w = 0; w < NW; ++w) {
      const uint32_t rowbase = (uint32_t)(b * NW + w) * ND + (uint32_t)e0;
      #pragma unroll
      for (int j = 0; j < 4; ++j)
        v[w][j] = fmaf(0.01f, noise_z(nk0, nk1, rowbase + (uint32_t)j), v[w][j]);
      p[w] = v[w][0]*v[w][0] + v[w][1]*v[w][1] + v[w][2]*v[w][2] + v[w][3]*v[w][3];
    }
    block_sum6(p, red);
    #pragma unroll
    for (int w = 0; w < NW; ++w) {
      const float inv = 1.0f / (sqrtf(p[w]) + 1e-8f);
      #pragma unroll
      for (int j = 0; j < 4; ++j) v[w][j] *= inv;
    }
  }
  #pragma unroll
  for (int w = 0; w < NW; ++w) {
    float4 a; a.x=v[w][0]; a.y=v[w][1]; a.z=v[w][2]; a.w=v[w][3];
    *reinterpret_cast<float4*>(&xs[w][e0]) = a;
  }
  __syncthreads();

  // ---- phase 2: cross-head mean (coupling) ----
  for (int idx = t; idx < NW * NDH; idx += BT) {   // 3 iters
    const int w = idx >> 7, el = idx & 127;
    float s = 0.0f;
    #pragma unroll
    for (int hh = 0; hh < NH; ++hh) s += xs[w][hh * NDH + el];
    mh[w][el] = s * 0.125f;
  }
  __syncthreads();

  // ---- phase 3: drift matmul, float4 x broadcasts (2-way bank alias = free)
  float acc[NW][4];
  #pragma unroll
  for (int w = 0; w < NW; ++w)
    #pragma unroll
    for (int j = 0; j < 4; ++j) acc[w][j] = 0.0f;

  const float4* Mp = reinterpret_cast<const float4*>(M) + (size_t)h * (NDH * 32) + lc;
  #pragma unroll 2
  for (int d4 = 0; d4 < NDH / 4; ++d4) {
    float xv[NW][4];
    #pragma unroll
    for (int w = 0; w < NW; ++w) {
      const float4 q = *reinterpret_cast<const float4*>(&xs[w][h * NDH + (d4 << 2)]);
      xv[w][0]=q.x; xv[w][1]=q.y; xv[w][2]=q.z; xv[w][3]=q.w;
    }
    float4 mv[4];
    #pragma unroll
    for (int jj = 0; jj < 4; ++jj) mv[jj] = Mp[(size_t)((d4 << 2) + jj) * 32];
    #pragma unroll
    for (int jj = 0; jj < 4; ++jj) {
      #pragma unroll
      for (int w = 0; w < NW; ++w) {
        const float xd = xv[w][jj];
        acc[w][0] = fmaf(xd, mv[jj].x, acc[w][0]);
        acc[w][1] = fmaf(xd, mv[jj].y, acc[w][1]);
        acc[w][2] = fmaf(xd, mv[jj].z, acc[w][2]);
        acc[w][3] = fmaf(xd, mv[jj].w, acc[w][3]);
      }
    }
  }

  // ---- phase 4: Euler step on own 4 cols ----
  #pragma unroll
  for (int w = 0; w < NW; ++w) {
    const float4 sg = *reinterpret_cast<const float4*>(
        signal + (size_t)(b * NW + w) * ND + e0);
    const float4 xx = *reinterpret_cast<const float4*>(&xs[w][e0]);
    const float4 hh = *reinterpret_cast<const float4*>(&mh[w][e0 & 127]);
    const float sgf[4] = {sg.x, sg.y, sg.z, sg.w};
    const float xxf[4] = {xx.x, xx.y, xx.z, xx.w};
    const float mhf[4] = {hh.x, hh.y, hh.z, hh.w};
    #pragma unroll
    for (int j = 0; j < 4; ++j) {
      const float out = -acc[w][j] + C_COUP * (mhf[j] - xxf[j]) + sgf[j];
      acc[w][j] = fmaf(C_DT, out, xxf[j]);
    }
  }

  // ---- phase 5: clamp_norm (batched), write Sn, keep normed cols in regs ----
  float p[NW];
  #pragma unroll
  for (int w = 0; w < NW; ++w)
    p[w] = acc[w][0]*acc[w][0] + acc[w][1]*acc[w][1] +
           acc[w][2]*acc[w][2] + acc[w][3]*acc[w][3];
  block_sum6(p, red);
  float nn[NW][4];
  #pragma unroll
  for (int w = 0; w < NW; ++w) {
    const float n = sqrtf(p[w]);
    const float scale = fminf(fmaxf(n, 1e-3f), 12.0f) / fmaxf(n, 1e-8f);
    const float inv_norm = 1.0f / (n * scale + 1e-12f);
    float4 o;
    o.x = acc[w][0]*scale; o.y = acc[w][1]*scale;
    o.z = acc[w][2]*scale; o.w = acc[w][3]*scale;
    *reinterpret_cast<float4*>(Sout + (size_t)(b * NW + w) * ND + e0) = o;
    nn[w][0]=o.x*inv_norm; nn[w][1]=o.y*inv_norm;
    nn[w][2]=o.z*inv_norm; nn[w][3]=o.w*inv_norm;
  }

  // ---- phase 6: tension from register-resident normed cols ----
  float pc[NW];
  #pragma unroll
  for (int w = 0; w < NW; ++w) pc[w] = 0.0f;
  #pragma unroll
  for (int j = 0; j < 4; ++j) {
    float md = 0.0f;
    #pragma unroll
    for (int w = 0; w < NW; ++w) md += nn[w][j];
    md *= (1.0f / 6.0f);
    #pragma unroll
    for (int w = 0; w < NW; ++w) pc[w] = fmaf(nn[w][j], md, pc[w]);
  }
  block_sum6(pc, red);

  if (t == 0) {
    const float cos_sum = pc[0]+pc[1]+pc[2]+pc[3]+pc[4]+pc[5];
    const float T = 1.0f - cos_sum * (1.0f / 6.0f);
    atomicAdd(&flags->sum_T, T);
    if (T < C_TOL)   atomicAdd(&flags->cnt_low, 1);
    if (T > C_THIGH) atomicAdd(&flags->cnt_high, 1);
    __threadfence();
    const int ticket = atomicAdd(&flags->arrived, 1);
    if (ticket == NB - 1) {
      const float sT = atomicAdd(&flags->sum_T, 0.0f);
      const int cl = atomicAdd(&flags->cnt_low, 0);
      const int ch = atomicAdd(&flags->cnt_high, 0);
      curve[step_k] = sT * (1.0f / 2048.0f);
      const int nd = (cl == NB) ? 1 : 0;
      flags->apply_noise = (!nd && ch > 0) ? 1 : 0;
      flags->done = nd;
      flags->sum_T = 0.0f; flags->cnt_low = 0; flags->cnt_high = 0;
      flags->arrived = 0;
      __threadfence();
    }
  }
}

// trailing noise for the final step (pending noise not consumed by a next step)
__global__ __launch_bounds__(256) void noise_kernel(float* __restrict__ S,
                                                    const Flags* __restrict__ flags,
                                                    const uint32_t k0, const uint32_t k1) {
  if (!flags->apply_noise) return;
  __shared__ float red[4];
  const int t = threadIdx.x;
  const uint32_t base = (uint32_t)blockIdx.x * ND + (t << 2);
  const float4 s = *reinterpret_cast<const float4*>(S + base);
  float v[4] = {s.x, s.y, s.z, s.w};
  #pragma unroll
  for (int j = 0; j < 4; ++j)
    v[j] = fmaf(0.01f, noise_z(k0, k1, base + (uint32_t)j), v[j]);
  const float p2 = v[0]*v[0] + v[1]*v[1] + v[2]*v[2] + v[3]*v[3];
  const float n2 = block_sum4(p2, red);
  const float inv = 1.0f / (sqrtf(n2) + 1e-8f);
  float4 o;
  o.x = v[0]*inv; o.y = v[1]*inv; o.z = v[2]*inv; o.w = v[3]*inv;
  *reinterpret_cast<float4*>(S + base) = o;
}

extern "C" void kernel_launch(void* const* d_in, const int* in_sizes, int n_in,
                              void* d_out, int out_size, void* d_ws, size_t ws_size,
                              hipStream_t stream) {
  const float* S0     = (const float*)d_in[0];
  const float* signal = (const float*)d_in[1];
  const float* U      = (const float*)d_in[2];
  const float* V      = (const float*)d_in[3];
  float* out   = (float*)d_out;
  float* curve = out + NTOT;
  Flags* flags = (Flags*)d_ws;
  float* M = (float*)((char*)d_ws + 512);   // 512 KB for M, after flags

  init_kernel<<<1, 32, 0, stream>>>(flags, curve);
  precompute_M<<<NH * NDH, 128, 0, stream>>>(U, V, M);

  // fold_in(key(1), k) for k=0..15 on host: threefry((0,1), (0,k))
  uint32_t K0[NSTEPS], K1[NSTEPS];
  for (uint32_t k = 0; k < NSTEPS; ++k) tf2x32(0u, 1u, 0u, k, K0[k], K1[k]);

  for (int k = 0; k < NSTEPS; ++k) {
    // step k consumes the pending noise of step k-1 (key K[k-1])
    step_kernel<<<NB, BT, 0, stream>>>(
        k == 0 ? S0 : out, out, signal, M, flags, curve, k,
        k > 0 ? K0[k - 1] : 0u, k > 0 ? K1[k - 1] : 0u, k > 0 ? 1 : 0);
  }
  noise_kernel<<<NB * NW, 256, 0, stream>>>(out, flags, K0[NSTEPS - 1], K1[NSTEPS - 1]);
}